// Round 9
// baseline (541.768 us; speedup 1.0000x reference)
//
#include <hip/hip_runtime.h>
#include <stdint.h>

#define NN 8192
#define FD 256
#define LOG2E 1.44269504088896340736f
#define SPLIT 8
#define JSLICE (NN / SPLIT)      // 1024 j per gat block
#define NIT (JSLICE / 32)        // 32 iterations of 32 j (16 KB B-chunk each)
#define PASSES 3                 // idempotent re-runs (num/den both scale; ratio cancels)

typedef __attribute__((ext_vector_type(8))) __bf16 bf16x8;
typedef __attribute__((ext_vector_type(4))) float f32x4;

__device__ __forceinline__ unsigned short f2bf(float x) {
    unsigned u = __float_as_uint(x);
    u = u + 0x7fffu + ((u >> 16) & 1u);   // RNE; no NaNs in this problem
    return (unsigned short)(u >> 16);
}
__device__ __forceinline__ bf16x8 ld_bf8(const unsigned short* p) {
    uint4 v = *(const uint4*)p;
    return __builtin_bit_cast(bf16x8, v);
}
// pack two f32 -> (bf16(b)<<16)|bf16(a) by truncation, single v_perm
__device__ __forceinline__ unsigned pack_trunc2(float a, float b) {
    return __builtin_amdgcn_perm(__float_as_uint(b), __float_as_uint(a), 0x07060302u);
}
// Non-sinkable async global->LDS, 16 B/lane. HW uses wave-uniform LDS base + lane*16.
__device__ __forceinline__ void async_ld16(const void* g, void* lds) {
    __builtin_amdgcn_global_load_lds(
        (const __attribute__((address_space(1))) void*)g,
        (__attribute__((address_space(3))) void*)lds, 16, 0, 0);
}

// ---------------- Kernel 0: WbT[f][k] = bf16(W[k][f]) ----------------
__global__ __launch_bounds__(256) void wtrans_kernel(const float* __restrict__ W,
                                                     unsigned short* __restrict__ WbT) {
    int idx = blockIdx.x * 256 + threadIdx.x;   // 65536 elems
    int k = idx >> 8, f = idx & 255;
    WbT[f * 256 + k] = f2bf(W[idx]);
}

// ---------------- Kernel 1: adjpack — stream adj into row-major bitmask adjB[i][w] ----------------
__global__ __launch_bounds__(256) void adjpack_kernel(const int* __restrict__ adj,
                                                      unsigned* __restrict__ adjB) {
    int t = threadIdx.x;
    int l = t & 63, w = t >> 6;
    int i = blockIdx.x * 4 + w;
    const int* arow = adj + (size_t)i * NN;
    unsigned* brow = adjB + (size_t)i * (NN / 32);
    #pragma unroll 2
    for (int c = 0; c < 32; ++c) {
        int base = c * 256;
        int v0 = arow[base + l];
        int v1 = arow[base + 64 + l];
        int v2 = arow[base + 128 + l];
        int v3 = arow[base + 192 + l];
        unsigned long long b0 = __ballot(v0 > 0);
        unsigned long long b1 = __ballot(v1 > 0);
        unsigned long long b2 = __ballot(v2 > 0);
        unsigned long long b3 = __ballot(v3 > 0);
        if (l == 0) {
            uint4 lo = make_uint4((unsigned)b0, (unsigned)(b0 >> 32),
                                  (unsigned)b1, (unsigned)(b1 >> 32));
            uint4 hi = make_uint4((unsigned)b2, (unsigned)(b2 >> 32),
                                  (unsigned)b3, (unsigned)(b3 >> 32));
            *(uint4*)(brow + c * 8) = lo;
            *(uint4*)(brow + c * 8 + 4) = hi;
        }
    }
}

// ---------------- Kernel 1b: transpose bitmask: adjB_T[w][i] = adjB[i][w] ----------------
__global__ __launch_bounds__(256) void btrans_kernel(const unsigned* __restrict__ rm,
                                                     unsigned* __restrict__ tm) {
    __shared__ unsigned tile[64 * 65];
    int t = threadIdx.x;
    int l = t & 63, r0 = t >> 6;
    int i0 = (blockIdx.x & 127) * 64;
    int w0 = (blockIdx.x >> 7) * 64;
    #pragma unroll
    for (int k = 0; k < 16; ++k) {
        int r = k * 4 + r0;
        tile[r * 65 + l] = rm[(size_t)(i0 + r) * (NN / 32) + w0 + l];
    }
    __syncthreads();
    #pragma unroll
    for (int k = 0; k < 16; ++k) {
        int wi = k * 4 + r0;
        tm[(size_t)(w0 + wi) * NN + i0 + l] = tile[l * 65 + wi];
    }
}

// ---------------- Kernel 2: PB = MFMA-B-fragment-packed (h@W+b); fused f1/f2 ----------------
// PB unit (jc, fg, lane l=(cl,q)): 8 bf16 = Wh[j = jc*32 + q*8 .. +7][f = fg*16+cl].
__global__ __launch_bounds__(256) void gemm1_kernel(const float* __restrict__ h,
                                                    const unsigned short* __restrict__ WbT,
                                                    const float* __restrict__ bias,
                                                    const float* __restrict__ av,
                                                    unsigned short* __restrict__ PBu,
                                                    float* __restrict__ f1p,
                                                    float* __restrict__ f2p) {
    __shared__ float Wh_s[256 * 33];   // [f][i-local], +1 pad
    __shared__ float red_s[2 * 8 * 32];
    int t = threadIdx.x;
    int l = t & 63, w = t >> 6;
    int i0 = blockIdx.x * 32;
    int fbase = w * 64;
    int cl = l & 15, q = l >> 4;

    f32x4 acc[2][4] = {};
    const float* hA0 = h + (size_t)(i0 + cl) * FD;
    const float* hA1 = h + (size_t)(i0 + 16 + cl) * FD;

    #pragma unroll
    for (int ks = 0; ks < 8; ++ks) {
        int kk = ks * 32 + q * 8;
        union { unsigned short u[8]; bf16x8 v; } ua0, ua1;
        float4 x0 = *(const float4*)(hA0 + kk);
        float4 x1 = *(const float4*)(hA0 + kk + 4);
        float4 y0 = *(const float4*)(hA1 + kk);
        float4 y1 = *(const float4*)(hA1 + kk + 4);
        ua0.u[0]=f2bf(x0.x); ua0.u[1]=f2bf(x0.y); ua0.u[2]=f2bf(x0.z); ua0.u[3]=f2bf(x0.w);
        ua0.u[4]=f2bf(x1.x); ua0.u[5]=f2bf(x1.y); ua0.u[6]=f2bf(x1.z); ua0.u[7]=f2bf(x1.w);
        ua1.u[0]=f2bf(y0.x); ua1.u[1]=f2bf(y0.y); ua1.u[2]=f2bf(y0.z); ua1.u[3]=f2bf(y0.w);
        ua1.u[4]=f2bf(y1.x); ua1.u[5]=f2bf(y1.y); ua1.u[6]=f2bf(y1.z); ua1.u[7]=f2bf(y1.w);
        #pragma unroll
        for (int bg = 0; bg < 4; ++bg) {
            bf16x8 bF = ld_bf8(WbT + (fbase + bg * 16 + cl) * 256 + kk);
            acc[0][bg] = __builtin_amdgcn_mfma_f32_16x16x32_bf16(ua0.v, bF, acc[0][bg], 0, 0, 0);
            acc[1][bg] = __builtin_amdgcn_mfma_f32_16x16x32_bf16(ua1.v, bF, acc[1][bg], 0, 0, 0);
        }
    }

    // C layout: col = lane&15, row = (lane>>4)*4 + reg   [m89-verified]
    #pragma unroll
    for (int mt = 0; mt < 2; ++mt)
        #pragma unroll
        for (int bg = 0; bg < 4; ++bg)
            #pragma unroll
            for (int e = 0; e < 4; ++e) {
                int il = mt * 16 + q * 4 + e;
                int fl = fbase + bg * 16 + cl;
                Wh_s[fl * 33 + il] = acc[mt][bg][e] + bias[fl];
            }
    __syncthreads();
    {   // emit packed-B fragments: this block is j-chunk jc = blockIdx exactly
        size_t jcBase = (size_t)blockIdx.x * 8192;   // 16 fg * 64 lanes * 8 elems
        #pragma unroll
        for (int u = 0; u < 4; ++u) {
            int fg = u * 4 + (t >> 6);
            int ll = t & 63;
            int c2 = ll & 15, q2 = ll >> 4;
            const float* src = &Wh_s[(fg * 16 + c2) * 33 + q2 * 8];
            union { unsigned short us[8]; uint4 v; } p;
            #pragma unroll
            for (int e = 0; e < 8; ++e) p.us[e] = f2bf(src[e]);
            *(uint4*)(PBu + jcBase + fg * 512 + ll * 8) = p.v;
        }
    }
    // fused f1/f2 partials: thread t -> i = t&31, f-chunk = t>>5 (32 f's)
    {
        int i = t & 31, fc = t >> 5;
        float s1 = 0.f, s2 = 0.f;
        #pragma unroll
        for (int fo = 0; fo < 32; ++fo) {
            int f = fc * 32 + fo;
            float wv = Wh_s[f * 33 + i];
            s1 += wv * av[f];
            s2 += wv * av[256 + f];
        }
        red_s[fc * 32 + i] = s1;
        red_s[256 + fc * 32 + i] = s2;
    }
    __syncthreads();
    if (t < 32) {
        float s = 0.f;
        #pragma unroll
        for (int fc = 0; fc < 8; ++fc) s += red_s[fc * 32 + t];
        f1p[i0 + t] = s * LOG2E;
    } else if (t < 64) {
        int i = t - 32;
        float s = 0.f;
        #pragma unroll
        for (int fc = 0; fc < 8; ++fc) s += red_s[256 + fc * 32 + i];
        f2p[i0 + i] = s * LOG2E;
    }
}

// ---------------- Kernel 3: fused GAT — DIAGNOSTIC 3-pass, 1-iter phases, 3 blocks/CU ----------------
// PASSES re-runs of the phase loop WITHOUT acc reset: num & den both scale x3, the
// softmax ratio cancels exactly -> output unchanged, but gat dur ~3x => visible in
// top-5 profile with full counters. 16 KB dbuf chunks (1 iter/phase), LDS 44 KB.
__global__ __launch_bounds__(256, 3) void gat_kernel(const unsigned* __restrict__ adjBT,
                                                     const unsigned short* __restrict__ PBu,
                                                     const float* __restrict__ f1p,
                                                     const float* __restrict__ f2p,
                                                     float* __restrict__ num,
                                                     float* __restrict__ den) {
    __shared__ __align__(16) unsigned short Bs[2][8192];       // 32 KB dbuf (16 KB/chunk)
    __shared__ unsigned mask_s[NIT * 64];                      // 8 KB
    __shared__ float f2_s[JSLICE];                             // 4 KB

    int t = threadIdx.x;
    int l = t & 63, w = t >> 6;
    int s = blockIdx.x & 7;              // j-split (XCD-pinned under round-robin)
    int strip = blockIdx.x >> 3;
    int i0b = strip * 64;                // block's 64 rows
    int j0 = s * JSLICE;
    int jw0 = j0 / 32;
    int cl = l & 15, q = l >> 4;

    // ---- stage masks (adjBT[w][i], coalesced) + f2 slice, once ----
    #pragma unroll
    for (int c = 0; c < 8; ++c) {
        int idx = c * 256 + t;           // idx = jt*64 + rl
        int jt = idx >> 6, rl = idx & 63;
        mask_s[idx] = adjBT[(size_t)(jw0 + jt) * NN + i0b + rl];
    }
    *(float4*)&f2_s[t * 4] = *(const float4*)(f2p + j0 + t * 4);

    const char* pbBase = (const char*)(PBu + (size_t)jw0 * 8192);  // byte base of slice
    // stage chunk 0 into buf 0: 16 KB, thread t covers bytes k*4096 + t*16
    #pragma unroll
    for (int k = 0; k < 4; ++k)
        async_ld16(pbBase + k * 4096 + t * 16, (char*)&Bs[0][0] + k * 4096 + t * 16);

    float f1v = f1p[i0b + w * 16 + cl];  // wave w owns rows i0b + w*16 .. +15

    f32x4 acc[16] = {};
    float rs = 0.f;

    #pragma unroll 1
    for (int g = 0; g < PASSES * NIT; ++g) {
        __syncthreads();   // drains async staging of buf[g&1] (+ prologue LDS on g=0)
        if (g + 1 < PASSES * NIT) {
            const char* src = pbBase + (size_t)((g + 1) & (NIT - 1)) * 16384;
            char* dst = (char*)&Bs[(g + 1) & 1][0];
            #pragma unroll
            for (int k = 0; k < 4; ++k)
                async_ld16(src + k * 4096 + t * 16, dst + k * 4096 + t * 16);
        }
        int jt = g & (NIT - 1);
        unsigned mw = mask_s[jt * 64 + w * 16 + cl];
        float4 F0 = *(const float4*)&f2_s[jt * 32 + q * 8];
        float4 F1 = *(const float4*)&f2_s[jt * 32 + q * 8 + 4];

        unsigned bits = mw >> (q * 8);
        float fe[8] = {F0.x, F0.y, F0.z, F0.w, F1.x, F1.y, F1.z, F1.w};
        float wv[8];
        #pragma unroll
        for (int e = 0; e < 8; ++e) {
            float sv = f1v + fe[e];
            sv = fmaxf(sv, 0.2f * sv);           // leaky_relu, pre-scaled by log2e
            float x = __builtin_amdgcn_exp2f(sv);
            x = (bits >> e) & 1 ? x : 0.f;
            rs += x;
            wv[e] = x;
        }
        union { unsigned uu[4]; bf16x8 v; } af;
        af.uu[0] = pack_trunc2(wv[0], wv[1]);
        af.uu[1] = pack_trunc2(wv[2], wv[3]);
        af.uu[2] = pack_trunc2(wv[4], wv[5]);
        af.uu[3] = pack_trunc2(wv[6], wv[7]);

        const unsigned short* bu = &Bs[g & 1][0] + l * 8;
        #pragma unroll
        for (int fg = 0; fg < 16; ++fg) {
            bf16x8 B = ld_bf8(bu + fg * 512);
            acc[fg] = __builtin_amdgcn_mfma_f32_16x16x32_bf16(af.v, B, acc[fg], 0, 0, 0);
        }
    }

    // rowsum (x PASSES) for row cl of wave's group; acc also x PASSES -> ratio cancels
    rs += __shfl_xor(rs, 16);
    rs += __shfl_xor(rs, 32);
    if (l < 16) den[(size_t)s * NN + i0b + w * 16 + l] = rs;

    // partial numerator: C layout row r = q*4+e, col = fg*16+cl
    float* nrow = num + (size_t)s * NN * FD;
    #pragma unroll
    for (int e = 0; e < 4; ++e) {
        int r = i0b + w * 16 + q * 4 + e;
        #pragma unroll
        for (int fg = 0; fg < 16; ++fg)
            nrow[(size_t)r * FD + fg * 16 + cl] = acc[fg][e];
    }
}

// ---------------- Kernel 4: combine j-split partials ----------------
__global__ __launch_bounds__(256) void combine_kernel(const float* __restrict__ num,
                                                      const float* __restrict__ den,
                                                      float* __restrict__ out) {
    int idx = blockIdx.x * 256 + threadIdx.x;   // 2M elems; i uniform per block
    int i = idx >> 8;
    float nsum = 0.f, dsum = 0.f;
    #pragma unroll
    for (int s = 0; s < SPLIT; ++s) {
        nsum += num[(size_t)s * NN * FD + idx];
        dsum += den[(size_t)s * NN + i];
    }
    out[idx] = nsum / dsum;
}

extern "C" void kernel_launch(void* const* d_in, const int* in_sizes, int n_in,
                              void* d_out, int out_size, void* d_ws, size_t ws_size,
                              hipStream_t stream) {
    const float* h   = (const float*)d_in[0];
    const int*   adj = (const int*)d_in[1];
    const float* W   = (const float*)d_in[2];
    const float* b   = (const float*)d_in[3];
    const float* a   = (const float*)d_in[4];
    float* out = (float*)d_out;

    char* ws = (char*)d_ws;
    unsigned short* PBu = (unsigned short*)ws;                          // 4 MB packed Wh fragments
    unsigned short* WbT = (unsigned short*)(ws + (4u << 20));           // 128 KB
    float* f1p = (float*)(ws + (4u << 20) + (128u << 10));              // 32 KB
    float* f2p = f1p + NN;                                              // 32 KB
    float* den = f2p + NN;                                              // SPLIT*NN f32 = 256 KB
    unsigned* adjB  = (unsigned*)(ws + (8u << 20));                     // 8 MB row-major bitmask
    unsigned* adjBT = (unsigned*)(ws + (16u << 20));                    // 8 MB transposed bitmask
    float* num = (float*)(ws + (24u << 20));                            // SPLIT*8 MB = 64 MB

    adjpack_kernel<<<NN / 4, 256, 0, stream>>>(adj, adjB);
    wtrans_kernel<<<256, 256, 0, stream>>>(W, WbT);
    btrans_kernel<<<512, 256, 0, stream>>>(adjB, adjBT);
    gemm1_kernel<<<256, 256, 0, stream>>>(h, WbT, b, a, PBu, f1p, f2p);
    gat_kernel<<<128 * SPLIT, 256, 0, stream>>>(adjBT, PBu, f1p, f2p, num, den);
    combine_kernel<<<NN * FD / 256, 256, 0, stream>>>(num, den, out);
}

// Round 10
// 460.881 us; speedup vs baseline: 1.1755x; 1.1755x over previous
//
#include <hip/hip_runtime.h>
#include <stdint.h>

#define NN 8192
#define FD 256
#define LOG2E 1.44269504088896340736f
#define SPLIT 8
#define JSLICE (NN / SPLIT)      // 1024 j per gat block
#define NIT (JSLICE / 32)        // 32 iterations of 32 j (16 KB B-chunk each)

typedef __attribute__((ext_vector_type(8))) __bf16 bf16x8;
typedef __attribute__((ext_vector_type(4))) float f32x4;

__device__ __forceinline__ unsigned short f2bf(float x) {
    unsigned u = __float_as_uint(x);
    u = u + 0x7fffu + ((u >> 16) & 1u);   // RNE; no NaNs in this problem
    return (unsigned short)(u >> 16);
}
__device__ __forceinline__ bf16x8 ld_bf8(const unsigned short* p) {
    uint4 v = *(const uint4*)p;
    return __builtin_bit_cast(bf16x8, v);
}
// pack two f32 -> (bf16(b)<<16)|bf16(a) by truncation, single v_perm
__device__ __forceinline__ unsigned pack_trunc2(float a, float b) {
    return __builtin_amdgcn_perm(__float_as_uint(b), __float_as_uint(a), 0x07060302u);
}
// Non-sinkable async global->LDS, 16 B/lane. HW uses wave-uniform LDS base + lane*16.
__device__ __forceinline__ void async_ld16(const void* g, void* lds) {
    __builtin_amdgcn_global_load_lds(
        (const __attribute__((address_space(1))) void*)g,
        (__attribute__((address_space(3))) void*)lds, 16, 0, 0);
}

// ---------------- Kernel 0: WbT[f][k] = bf16(W[k][f]) ----------------
__global__ __launch_bounds__(256) void wtrans_kernel(const float* __restrict__ W,
                                                     unsigned short* __restrict__ WbT) {
    int idx = blockIdx.x * 256 + threadIdx.x;   // 65536 elems
    int k = idx >> 8, f = idx & 255;
    WbT[f * 256 + k] = f2bf(W[idx]);
}

// ---------------- Kernel 1: adjpack — stream adj into row-major bitmask adjB[i][w] ----------------
__global__ __launch_bounds__(256) void adjpack_kernel(const int* __restrict__ adj,
                                                      unsigned* __restrict__ adjB) {
    int t = threadIdx.x;
    int l = t & 63, w = t >> 6;
    int i = blockIdx.x * 4 + w;
    const int* arow = adj + (size_t)i * NN;
    unsigned* brow = adjB + (size_t)i * (NN / 32);
    #pragma unroll 2
    for (int c = 0; c < 32; ++c) {
        int base = c * 256;
        int v0 = arow[base + l];
        int v1 = arow[base + 64 + l];
        int v2 = arow[base + 128 + l];
        int v3 = arow[base + 192 + l];
        unsigned long long b0 = __ballot(v0 > 0);
        unsigned long long b1 = __ballot(v1 > 0);
        unsigned long long b2 = __ballot(v2 > 0);
        unsigned long long b3 = __ballot(v3 > 0);
        if (l == 0) {
            uint4 lo = make_uint4((unsigned)b0, (unsigned)(b0 >> 32),
                                  (unsigned)b1, (unsigned)(b1 >> 32));
            uint4 hi = make_uint4((unsigned)b2, (unsigned)(b2 >> 32),
                                  (unsigned)b3, (unsigned)(b3 >> 32));
            *(uint4*)(brow + c * 8) = lo;
            *(uint4*)(brow + c * 8 + 4) = hi;
        }
    }
}

// ---------------- Kernel 1b: transpose bitmask: adjB_T[w][i] = adjB[i][w] ----------------
__global__ __launch_bounds__(256) void btrans_kernel(const unsigned* __restrict__ rm,
                                                     unsigned* __restrict__ tm) {
    __shared__ unsigned tile[64 * 65];
    int t = threadIdx.x;
    int l = t & 63, r0 = t >> 6;
    int i0 = (blockIdx.x & 127) * 64;
    int w0 = (blockIdx.x >> 7) * 64;
    #pragma unroll
    for (int k = 0; k < 16; ++k) {
        int r = k * 4 + r0;
        tile[r * 65 + l] = rm[(size_t)(i0 + r) * (NN / 32) + w0 + l];
    }
    __syncthreads();
    #pragma unroll
    for (int k = 0; k < 16; ++k) {
        int wi = k * 4 + r0;
        tm[(size_t)(w0 + wi) * NN + i0 + l] = tile[l * 65 + wi];
    }
}

// ---------------- Kernel 2: PB = MFMA-B-fragment-packed (h@W+b); fused f1/f2 ----------------
// PB unit (jc, fg, lane l=(cl,q)): 8 bf16 = Wh[j = jc*32 + q*8 .. +7][f = fg*16+cl].
__global__ __launch_bounds__(256) void gemm1_kernel(const float* __restrict__ h,
                                                    const unsigned short* __restrict__ WbT,
                                                    const float* __restrict__ bias,
                                                    const float* __restrict__ av,
                                                    unsigned short* __restrict__ PBu,
                                                    float* __restrict__ f1p,
                                                    float* __restrict__ f2p) {
    __shared__ float Wh_s[256 * 33];   // [f][i-local], +1 pad
    __shared__ float red_s[2 * 8 * 32];
    int t = threadIdx.x;
    int l = t & 63, w = t >> 6;
    int i0 = blockIdx.x * 32;
    int fbase = w * 64;
    int cl = l & 15, q = l >> 4;

    f32x4 acc[2][4] = {};
    const float* hA0 = h + (size_t)(i0 + cl) * FD;
    const float* hA1 = h + (size_t)(i0 + 16 + cl) * FD;

    #pragma unroll
    for (int ks = 0; ks < 8; ++ks) {
        int kk = ks * 32 + q * 8;
        union { unsigned short u[8]; bf16x8 v; } ua0, ua1;
        float4 x0 = *(const float4*)(hA0 + kk);
        float4 x1 = *(const float4*)(hA0 + kk + 4);
        float4 y0 = *(const float4*)(hA1 + kk);
        float4 y1 = *(const float4*)(hA1 + kk + 4);
        ua0.u[0]=f2bf(x0.x); ua0.u[1]=f2bf(x0.y); ua0.u[2]=f2bf(x0.z); ua0.u[3]=f2bf(x0.w);
        ua0.u[4]=f2bf(x1.x); ua0.u[5]=f2bf(x1.y); ua0.u[6]=f2bf(x1.z); ua0.u[7]=f2bf(x1.w);
        ua1.u[0]=f2bf(y0.x); ua1.u[1]=f2bf(y0.y); ua1.u[2]=f2bf(y0.z); ua1.u[3]=f2bf(y0.w);
        ua1.u[4]=f2bf(y1.x); ua1.u[5]=f2bf(y1.y); ua1.u[6]=f2bf(y1.z); ua1.u[7]=f2bf(y1.w);
        #pragma unroll
        for (int bg = 0; bg < 4; ++bg) {
            bf16x8 bF = ld_bf8(WbT + (fbase + bg * 16 + cl) * 256 + kk);
            acc[0][bg] = __builtin_amdgcn_mfma_f32_16x16x32_bf16(ua0.v, bF, acc[0][bg], 0, 0, 0);
            acc[1][bg] = __builtin_amdgcn_mfma_f32_16x16x32_bf16(ua1.v, bF, acc[1][bg], 0, 0, 0);
        }
    }

    // C layout: col = lane&15, row = (lane>>4)*4 + reg   [m89-verified]
    #pragma unroll
    for (int mt = 0; mt < 2; ++mt)
        #pragma unroll
        for (int bg = 0; bg < 4; ++bg)
            #pragma unroll
            for (int e = 0; e < 4; ++e) {
                int il = mt * 16 + q * 4 + e;
                int fl = fbase + bg * 16 + cl;
                Wh_s[fl * 33 + il] = acc[mt][bg][e] + bias[fl];
            }
    __syncthreads();
    {   // emit packed-B fragments: this block is j-chunk jc = blockIdx exactly
        size_t jcBase = (size_t)blockIdx.x * 8192;   // 16 fg * 64 lanes * 8 elems
        #pragma unroll
        for (int u = 0; u < 4; ++u) {
            int fg = u * 4 + (t >> 6);
            int ll = t & 63;
            int c2 = ll & 15, q2 = ll >> 4;
            const float* src = &Wh_s[(fg * 16 + c2) * 33 + q2 * 8];
            union { unsigned short us[8]; uint4 v; } p;
            #pragma unroll
            for (int e = 0; e < 8; ++e) p.us[e] = f2bf(src[e]);
            *(uint4*)(PBu + jcBase + fg * 512 + ll * 8) = p.v;
        }
    }
    // fused f1/f2 partials: thread t -> i = t&31, f-chunk = t>>5 (32 f's)
    {
        int i = t & 31, fc = t >> 5;
        float s1 = 0.f, s2 = 0.f;
        #pragma unroll
        for (int fo = 0; fo < 32; ++fo) {
            int f = fc * 32 + fo;
            float wv = Wh_s[f * 33 + i];
            s1 += wv * av[f];
            s2 += wv * av[256 + f];
        }
        red_s[fc * 32 + i] = s1;
        red_s[256 + fc * 32 + i] = s2;
    }
    __syncthreads();
    if (t < 32) {
        float s = 0.f;
        #pragma unroll
        for (int fc = 0; fc < 8; ++fc) s += red_s[fc * 32 + t];
        f1p[i0 + t] = s * LOG2E;
    } else if (t < 64) {
        int i = t - 32;
        float s = 0.f;
        #pragma unroll
        for (int fc = 0; fc < 8; ++fc) s += red_s[256 + fc * 32 + i];
        f2p[i0 + i] = s * LOG2E;
    }
}

// ---------------- Kernel 3: fused GAT — 1-iter phases, 3 blocks/CU, rowsum via MFMA ----------------
// Structure frozen from R9 diagnostic (53 us/pass): 16 KB dbuf chunks, 1 barrier/iter,
// __launch_bounds__(256,3). New: denominator = extra MFMA vs all-ones B fragment
// (C[m][n] = rowsum(m) for all n) — moves 8 adds/iter off the 48%-busy VALU pipe.
__global__ __launch_bounds__(256, 3) void gat_kernel(const unsigned* __restrict__ adjBT,
                                                     const unsigned short* __restrict__ PBu,
                                                     const float* __restrict__ f1p,
                                                     const float* __restrict__ f2p,
                                                     float* __restrict__ num,
                                                     float* __restrict__ den) {
    __shared__ __align__(16) unsigned short Bs[2][8192];       // 32 KB dbuf (16 KB/chunk)
    __shared__ unsigned mask_s[NIT * 64];                      // 8 KB
    __shared__ float f2_s[JSLICE];                             // 4 KB

    int t = threadIdx.x;
    int l = t & 63, w = t >> 6;
    int s = blockIdx.x & 7;              // j-split (XCD-pinned under round-robin)
    int strip = blockIdx.x >> 3;
    int i0b = strip * 64;                // block's 64 rows
    int j0 = s * JSLICE;
    int jw0 = j0 / 32;
    int cl = l & 15, q = l >> 4;

    // ---- stage masks (adjBT[w][i], coalesced) + f2 slice, once ----
    #pragma unroll
    for (int c = 0; c < 8; ++c) {
        int idx = c * 256 + t;           // idx = jt*64 + rl
        int jt = idx >> 6, rl = idx & 63;
        mask_s[idx] = adjBT[(size_t)(jw0 + jt) * NN + i0b + rl];
    }
    *(float4*)&f2_s[t * 4] = *(const float4*)(f2p + j0 + t * 4);

    const char* pbBase = (const char*)(PBu + (size_t)jw0 * 8192);  // byte base of slice
    // stage chunk 0 into buf 0: 16 KB, thread t covers bytes k*4096 + t*16
    #pragma unroll
    for (int k = 0; k < 4; ++k)
        async_ld16(pbBase + k * 4096 + t * 16, (char*)&Bs[0][0] + k * 4096 + t * 16);

    float f1v = f1p[i0b + w * 16 + cl];  // wave w owns rows i0b + w*16 .. +15

    // all-ones B fragment (bf16 1.0 = 0x3F80) for the rowsum MFMA
    const bf16x8 onesB = __builtin_bit_cast(bf16x8,
        make_uint4(0x3F803F80u, 0x3F803F80u, 0x3F803F80u, 0x3F803F80u));

    f32x4 acc[16] = {};
    f32x4 accR = {};                     // rowsum accumulator

    #pragma unroll 1
    for (int g = 0; g < NIT; ++g) {
        __syncthreads();   // drains async staging of buf[g&1] (+ prologue LDS on g=0)
        if (g + 1 < NIT) {
            const char* src = pbBase + (size_t)(g + 1) * 16384;
            char* dst = (char*)&Bs[(g + 1) & 1][0];
            #pragma unroll
            for (int k = 0; k < 4; ++k)
                async_ld16(src + k * 4096 + t * 16, dst + k * 4096 + t * 16);
        }
        unsigned mw = mask_s[g * 64 + w * 16 + cl];
        float4 F0 = *(const float4*)&f2_s[g * 32 + q * 8];
        float4 F1 = *(const float4*)&f2_s[g * 32 + q * 8 + 4];

        unsigned bits = mw >> (q * 8);
        float fe[8] = {F0.x, F0.y, F0.z, F0.w, F1.x, F1.y, F1.z, F1.w};
        float wv[8];
        #pragma unroll
        for (int e = 0; e < 8; ++e) {
            float sv = f1v + fe[e];
            sv = fmaxf(sv, 0.2f * sv);           // leaky_relu, pre-scaled by log2e
            float x = __builtin_amdgcn_exp2f(sv);
            x = (bits >> e) & 1 ? x : 0.f;
            wv[e] = x;
        }
        union { unsigned uu[4]; bf16x8 v; } af;
        af.uu[0] = pack_trunc2(wv[0], wv[1]);
        af.uu[1] = pack_trunc2(wv[2], wv[3]);
        af.uu[2] = pack_trunc2(wv[4], wv[5]);
        af.uu[3] = pack_trunc2(wv[6], wv[7]);

        const unsigned short* bu = &Bs[g & 1][0] + l * 8;
        #pragma unroll
        for (int fg = 0; fg < 16; ++fg) {
            bf16x8 B = ld_bf8(bu + fg * 512);
            acc[fg] = __builtin_amdgcn_mfma_f32_16x16x32_bf16(af.v, B, acc[fg], 0, 0, 0);
        }
        accR = __builtin_amdgcn_mfma_f32_16x16x32_bf16(af.v, onesB, accR, 0, 0, 0);
    }

    // denominator: accR C layout row = q*4+e, every col identical; cl==0 lanes write
    if (cl == 0) {
        #pragma unroll
        for (int e = 0; e < 4; ++e)
            den[(size_t)s * NN + i0b + w * 16 + q * 4 + e] = accR[e];
    }

    // partial numerator: C layout row r = q*4+e, col = fg*16+cl
    float* nrow = num + (size_t)s * NN * FD;
    #pragma unroll
    for (int e = 0; e < 4; ++e) {
        int r = i0b + w * 16 + q * 4 + e;
        #pragma unroll
        for (int fg = 0; fg < 16; ++fg)
            nrow[(size_t)r * FD + fg * 16 + cl] = acc[fg][e];
    }
}

// ---------------- Kernel 4: combine j-split partials ----------------
__global__ __launch_bounds__(256) void combine_kernel(const float* __restrict__ num,
                                                      const float* __restrict__ den,
                                                      float* __restrict__ out) {
    int idx = blockIdx.x * 256 + threadIdx.x;   // 2M elems; i uniform per block
    int i = idx >> 8;
    float nsum = 0.f, dsum = 0.f;
    #pragma unroll
    for (int s = 0; s < SPLIT; ++s) {
        nsum += num[(size_t)s * NN * FD + idx];
        dsum += den[(size_t)s * NN + i];
    }
    out[idx] = nsum / dsum;
}

extern "C" void kernel_launch(void* const* d_in, const int* in_sizes, int n_in,
                              void* d_out, int out_size, void* d_ws, size_t ws_size,
                              hipStream_t stream) {
    const float* h   = (const float*)d_in[0];
    const int*   adj = (const int*)d_in[1];
    const float* W   = (const float*)d_in[2];
    const float* b   = (const float*)d_in[3];
    const float* a   = (const float*)d_in[4];
    float* out = (float*)d_out;

    char* ws = (char*)d_ws;
    unsigned short* PBu = (unsigned short*)ws;                          // 4 MB packed Wh fragments
    unsigned short* WbT = (unsigned short*)(ws + (4u << 20));           // 128 KB
    float* f1p = (float*)(ws + (4u << 20) + (128u << 10));              // 32 KB
    float* f2p = f1p + NN;                                              // 32 KB
    float* den = f2p + NN;                                              // SPLIT*NN f32 = 256 KB
    unsigned* adjB  = (unsigned*)(ws + (8u << 20));                     // 8 MB row-major bitmask
    unsigned* adjBT = (unsigned*)(ws + (16u << 20));                    // 8 MB transposed bitmask
    float* num = (float*)(ws + (24u << 20));                            // SPLIT*8 MB = 64 MB

    adjpack_kernel<<<NN / 4, 256, 0, stream>>>(adj, adjB);
    wtrans_kernel<<<256, 256, 0, stream>>>(W, WbT);
    btrans_kernel<<<512, 256, 0, stream>>>(adjB, adjBT);
    gemm1_kernel<<<256, 256, 0, stream>>>(h, WbT, b, a, PBu, f1p, f2p);
    gat_kernel<<<128 * SPLIT, 256, 0, stream>>>(adjBT, PBu, f1p, f2p, num, den);
    combine_kernel<<<NN * FD / 256, 256, 0, stream>>>(num, den, out);
}

// Round 11
// 439.091 us; speedup vs baseline: 1.2338x; 1.0496x over previous
//
#include <hip/hip_runtime.h>
#include <stdint.h>

#define NN 8192
#define FD 256
#define LOG2E 1.44269504088896340736f
#define SPLIT 8
#define JSLICE (NN / SPLIT)      // 1024 j per gat block
#define NIT (JSLICE / 32)        // 32 iterations of 32 j (16 KB B-chunk each)

typedef __attribute__((ext_vector_type(8))) __bf16 bf16x8;
typedef __attribute__((ext_vector_type(4))) float f32x4;

__device__ __forceinline__ unsigned short f2bf(float x) {
    unsigned u = __float_as_uint(x);
    u = u + 0x7fffu + ((u >> 16) & 1u);   // RNE; no NaNs in this problem
    return (unsigned short)(u >> 16);
}
__device__ __forceinline__ bf16x8 ld_bf8(const unsigned short* p) {
    uint4 v = *(const uint4*)p;
    return __builtin_bit_cast(bf16x8, v);
}
// pack two f32 -> (bf16(b)<<16)|bf16(a) by truncation, single v_perm
__device__ __forceinline__ unsigned pack_trunc2(float a, float b) {
    return __builtin_amdgcn_perm(__float_as_uint(b), __float_as_uint(a), 0x07060302u);
}
// Non-sinkable async global->LDS, 16 B/lane. HW uses wave-uniform LDS base + lane*16.
__device__ __forceinline__ void async_ld16(const void* g, void* lds) {
    __builtin_amdgcn_global_load_lds(
        (const __attribute__((address_space(1))) void*)g,
        (__attribute__((address_space(3))) void*)lds, 16, 0, 0);
}

// ---------------- Kernel 0: WbT[f][k] = bf16(W[k][f]) ----------------
__global__ __launch_bounds__(256) void wtrans_kernel(const float* __restrict__ W,
                                                     unsigned short* __restrict__ WbT) {
    int idx = blockIdx.x * 256 + threadIdx.x;   // 65536 elems
    int k = idx >> 8, f = idx & 255;
    WbT[f * 256 + k] = f2bf(W[idx]);
}

// ---------------- Kernel 1: PB = MFMA-B-fragment-packed (h@W+b); fused f1/f2 ----------------
// PB unit (jc, fg, lane l=(cl,q)): 8 bf16 = Wh[j = jc*32 + q*8 .. +7][f = fg*16+cl].
// Block b -> chunk jc = (b&7)*32 + (b>>3): chunk jc (split jc/32 = b%8) is written by
// XCD b%8 == the XCD that gat (s = blockIdx&7) will read it on -> PB stays XCD-local.
__global__ __launch_bounds__(256) void gemm1_kernel(const float* __restrict__ h,
                                                    const unsigned short* __restrict__ WbT,
                                                    const float* __restrict__ bias,
                                                    const float* __restrict__ av,
                                                    unsigned short* __restrict__ PBu,
                                                    float* __restrict__ f1p,
                                                    float* __restrict__ f2p) {
    __shared__ float Wh_s[256 * 33];   // [f][i-local], +1 pad
    __shared__ float red_s[2 * 8 * 32];
    int t = threadIdx.x;
    int l = t & 63, w = t >> 6;
    int jc = (blockIdx.x & 7) * 32 + (blockIdx.x >> 3);
    int i0 = jc * 32;
    int fbase = w * 64;
    int cl = l & 15, q = l >> 4;

    f32x4 acc[2][4] = {};
    const float* hA0 = h + (size_t)(i0 + cl) * FD;
    const float* hA1 = h + (size_t)(i0 + 16 + cl) * FD;

    #pragma unroll
    for (int ks = 0; ks < 8; ++ks) {
        int kk = ks * 32 + q * 8;
        union { unsigned short u[8]; bf16x8 v; } ua0, ua1;
        float4 x0 = *(const float4*)(hA0 + kk);
        float4 x1 = *(const float4*)(hA0 + kk + 4);
        float4 y0 = *(const float4*)(hA1 + kk);
        float4 y1 = *(const float4*)(hA1 + kk + 4);
        ua0.u[0]=f2bf(x0.x); ua0.u[1]=f2bf(x0.y); ua0.u[2]=f2bf(x0.z); ua0.u[3]=f2bf(x0.w);
        ua0.u[4]=f2bf(x1.x); ua0.u[5]=f2bf(x1.y); ua0.u[6]=f2bf(x1.z); ua0.u[7]=f2bf(x1.w);
        ua1.u[0]=f2bf(y0.x); ua1.u[1]=f2bf(y0.y); ua1.u[2]=f2bf(y0.z); ua1.u[3]=f2bf(y0.w);
        ua1.u[4]=f2bf(y1.x); ua1.u[5]=f2bf(y1.y); ua1.u[6]=f2bf(y1.z); ua1.u[7]=f2bf(y1.w);
        #pragma unroll
        for (int bg = 0; bg < 4; ++bg) {
            bf16x8 bF = ld_bf8(WbT + (fbase + bg * 16 + cl) * 256 + kk);
            acc[0][bg] = __builtin_amdgcn_mfma_f32_16x16x32_bf16(ua0.v, bF, acc[0][bg], 0, 0, 0);
            acc[1][bg] = __builtin_amdgcn_mfma_f32_16x16x32_bf16(ua1.v, bF, acc[1][bg], 0, 0, 0);
        }
    }

    // C layout: col = lane&15, row = (lane>>4)*4 + reg   [m89-verified]
    #pragma unroll
    for (int mt = 0; mt < 2; ++mt)
        #pragma unroll
        for (int bg = 0; bg < 4; ++bg)
            #pragma unroll
            for (int e = 0; e < 4; ++e) {
                int il = mt * 16 + q * 4 + e;
                int fl = fbase + bg * 16 + cl;
                Wh_s[fl * 33 + il] = acc[mt][bg][e] + bias[fl];
            }
    __syncthreads();
    {   // emit packed-B fragments for chunk jc
        size_t jcBase = (size_t)jc * 8192;   // 16 fg * 64 lanes * 8 elems
        #pragma unroll
        for (int u = 0; u < 4; ++u) {
            int fg = u * 4 + (t >> 6);
            int ll = t & 63;
            int c2 = ll & 15, q2 = ll >> 4;
            const float* src = &Wh_s[(fg * 16 + c2) * 33 + q2 * 8];
            union { unsigned short us[8]; uint4 v; } p;
            #pragma unroll
            for (int e = 0; e < 8; ++e) p.us[e] = f2bf(src[e]);
            *(uint4*)(PBu + jcBase + fg * 512 + ll * 8) = p.v;
        }
    }
    // fused f1/f2 partials: thread t -> i = t&31, f-chunk = t>>5 (32 f's)
    {
        int i = t & 31, fc = t >> 5;
        float s1 = 0.f, s2 = 0.f;
        #pragma unroll
        for (int fo = 0; fo < 32; ++fo) {
            int f = fc * 32 + fo;
            float wv = Wh_s[f * 33 + i];
            s1 += wv * av[f];
            s2 += wv * av[256 + f];
        }
        red_s[fc * 32 + i] = s1;
        red_s[256 + fc * 32 + i] = s2;
    }
    __syncthreads();
    if (t < 32) {
        float s = 0.f;
        #pragma unroll
        for (int fc = 0; fc < 8; ++fc) s += red_s[fc * 32 + t];
        f1p[i0 + t] = s * LOG2E;
    } else if (t < 64) {
        int i = t - 32;
        float s = 0.f;
        #pragma unroll
        for (int fc = 0; fc < 8; ++fc) s += red_s[256 + fc * 32 + i];
        f2p[i0 + i] = s * LOG2E;
    }
}

// ---------------- Kernel 2: megafused GAT — adj streamed + balloted in-kernel ----------------
// Grid = 128 strips x SPLIT; block = 256 thr (4 waves), 64 rows x 1024 j, 16 waves/CU.
// Phase g: barrier; async B stage (g+1); issue 8 adj loads (g+1, own 16 rows x 32 j);
// MFMA compute g (cover); 8 ballots -> dbuf mask LDS. adjpack/btrans kernels deleted.
__global__ __launch_bounds__(256, 4) void gat_kernel(const int* __restrict__ adj,
                                                     const unsigned short* __restrict__ PBu,
                                                     const float* __restrict__ f1p,
                                                     const float* __restrict__ f2p,
                                                     float* __restrict__ num,
                                                     float* __restrict__ den) {
    __shared__ __align__(16) unsigned short Bs[2][8192];       // 32 KB dbuf (16 KB/chunk)
    __shared__ unsigned mask_b[2][64];                         // 512 B dbuf (64 rows x 32 bits)
    __shared__ float f2_s[JSLICE];                             // 4 KB

    int t = threadIdx.x;
    int l = t & 63, w = t >> 6;
    int s = blockIdx.x & 7;              // j-split (XCD-pinned under round-robin)
    int strip = blockIdx.x >> 3;
    int i0b = strip * 64;                // block's 64 rows
    int j0 = s * JSLICE;
    int jw0 = j0 / 32;
    int cl = l & 15, q = l >> 4;

    // ---- prologue: f2 slice, B chunk 0 (async), masks for g=0 ----
    *(float4*)&f2_s[t * 4] = *(const float4*)(f2p + j0 + t * 4);

    const char* pbBase = (const char*)(PBu + (size_t)jw0 * 8192);
    #pragma unroll
    for (int k = 0; k < 4; ++k)
        async_ld16(pbBase + k * 4096 + t * 16, (char*)&Bs[0][0] + k * 4096 + t * 16);

    // wave w ballots its own 16 rows: ballot k covers rows w*16+2k,+2k+1 x 32 j
    const int* arow = adj + (size_t)(i0b + w * 16 + (l >> 5)) * NN + j0 + (l & 31);
    {
        int v0 = arow[0 * 2 * NN], v1 = arow[1 * 2 * NN], v2 = arow[2 * 2 * NN], v3 = arow[3 * 2 * NN];
        int v4 = arow[4 * 2 * NN], v5 = arow[5 * 2 * NN], v6 = arow[6 * 2 * NN], v7 = arow[7 * 2 * NN];
        unsigned long long b0 = __ballot(v0 > 0), b1 = __ballot(v1 > 0);
        unsigned long long b2 = __ballot(v2 > 0), b3 = __ballot(v3 > 0);
        unsigned long long b4 = __ballot(v4 > 0), b5 = __ballot(v5 > 0);
        unsigned long long b6 = __ballot(v6 > 0), b7 = __ballot(v7 > 0);
        if (l == 0) {
            *(uint2*)&mask_b[0][w * 16 + 0]  = make_uint2((unsigned)b0, (unsigned)(b0 >> 32));
            *(uint2*)&mask_b[0][w * 16 + 2]  = make_uint2((unsigned)b1, (unsigned)(b1 >> 32));
            *(uint2*)&mask_b[0][w * 16 + 4]  = make_uint2((unsigned)b2, (unsigned)(b2 >> 32));
            *(uint2*)&mask_b[0][w * 16 + 6]  = make_uint2((unsigned)b3, (unsigned)(b3 >> 32));
            *(uint2*)&mask_b[0][w * 16 + 8]  = make_uint2((unsigned)b4, (unsigned)(b4 >> 32));
            *(uint2*)&mask_b[0][w * 16 + 10] = make_uint2((unsigned)b5, (unsigned)(b5 >> 32));
            *(uint2*)&mask_b[0][w * 16 + 12] = make_uint2((unsigned)b6, (unsigned)(b6 >> 32));
            *(uint2*)&mask_b[0][w * 16 + 14] = make_uint2((unsigned)b7, (unsigned)(b7 >> 32));
        }
    }

    float f1v = f1p[i0b + w * 16 + cl];  // wave w owns rows i0b + w*16 .. +15

    // all-ones B fragment (bf16 1.0 = 0x3F80) for the rowsum MFMA
    const bf16x8 onesB = __builtin_bit_cast(bf16x8,
        make_uint4(0x3F803F80u, 0x3F803F80u, 0x3F803F80u, 0x3F803F80u));

    f32x4 acc[16] = {};
    f32x4 accR = {};                     // rowsum accumulator

    #pragma unroll 1
    for (int g = 0; g < NIT; ++g) {
        __syncthreads();   // drains async B staging of buf[g&1], orders mask_b
        int a0, a1, a2, a3, a4, a5, a6, a7;
        if (g + 1 < NIT) {
            const char* src = pbBase + (size_t)(g + 1) * 16384;
            char* dst = (char*)&Bs[(g + 1) & 1][0];
            #pragma unroll
            for (int k = 0; k < 4; ++k)
                async_ld16(src + k * 4096 + t * 16, dst + k * 4096 + t * 16);
            int jo = (g + 1) * 32;
            a0 = arow[0 * 2 * NN + jo]; a1 = arow[1 * 2 * NN + jo];
            a2 = arow[2 * 2 * NN + jo]; a3 = arow[3 * 2 * NN + jo];
            a4 = arow[4 * 2 * NN + jo]; a5 = arow[5 * 2 * NN + jo];
            a6 = arow[6 * 2 * NN + jo]; a7 = arow[7 * 2 * NN + jo];
        }

        unsigned mw = mask_b[g & 1][w * 16 + cl];
        float4 F0 = *(const float4*)&f2_s[g * 32 + q * 8];
        float4 F1 = *(const float4*)&f2_s[g * 32 + q * 8 + 4];

        unsigned bits = mw >> (q * 8);
        float fe[8] = {F0.x, F0.y, F0.z, F0.w, F1.x, F1.y, F1.z, F1.w};
        float wv[8];
        #pragma unroll
        for (int e = 0; e < 8; ++e) {
            float sv = f1v + fe[e];
            sv = fmaxf(sv, 0.2f * sv);           // leaky_relu, pre-scaled by log2e
            float x = __builtin_amdgcn_exp2f(sv);
            x = (bits >> e) & 1 ? x : 0.f;
            wv[e] = x;
        }
        union { unsigned uu[4]; bf16x8 v; } af;
        af.uu[0] = pack_trunc2(wv[0], wv[1]);
        af.uu[1] = pack_trunc2(wv[2], wv[3]);
        af.uu[2] = pack_trunc2(wv[4], wv[5]);
        af.uu[3] = pack_trunc2(wv[6], wv[7]);

        const unsigned short* bu = &Bs[g & 1][0] + l * 8;
        #pragma unroll
        for (int fg = 0; fg < 16; ++fg) {
            bf16x8 B = ld_bf8(bu + fg * 512);
            acc[fg] = __builtin_amdgcn_mfma_f32_16x16x32_bf16(af.v, B, acc[fg], 0, 0, 0);
        }
        accR = __builtin_amdgcn_mfma_f32_16x16x32_bf16(af.v, onesB, accR, 0, 0, 0);

        if (g + 1 < NIT) {   // ballot g+1's masks (loads had the MFMA span to land)
            int nb = (g + 1) & 1;
            unsigned long long b0 = __ballot(a0 > 0), b1 = __ballot(a1 > 0);
            unsigned long long b2 = __ballot(a2 > 0), b3 = __ballot(a3 > 0);
            unsigned long long b4 = __ballot(a4 > 0), b5 = __ballot(a5 > 0);
            unsigned long long b6 = __ballot(a6 > 0), b7 = __ballot(a7 > 0);
            if (l == 0) {
                *(uint2*)&mask_b[nb][w * 16 + 0]  = make_uint2((unsigned)b0, (unsigned)(b0 >> 32));
                *(uint2*)&mask_b[nb][w * 16 + 2]  = make_uint2((unsigned)b1, (unsigned)(b1 >> 32));
                *(uint2*)&mask_b[nb][w * 16 + 4]  = make_uint2((unsigned)b2, (unsigned)(b2 >> 32));
                *(uint2*)&mask_b[nb][w * 16 + 6]  = make_uint2((unsigned)b3, (unsigned)(b3 >> 32));
                *(uint2*)&mask_b[nb][w * 16 + 8]  = make_uint2((unsigned)b4, (unsigned)(b4 >> 32));
                *(uint2*)&mask_b[nb][w * 16 + 10] = make_uint2((unsigned)b5, (unsigned)(b5 >> 32));
                *(uint2*)&mask_b[nb][w * 16 + 12] = make_uint2((unsigned)b6, (unsigned)(b6 >> 32));
                *(uint2*)&mask_b[nb][w * 16 + 14] = make_uint2((unsigned)b7, (unsigned)(b7 >> 32));
            }
        }
    }

    // denominator: accR C layout row = q*4+e, every col identical; cl==0 lanes write
    if (cl == 0) {
        #pragma unroll
        for (int e = 0; e < 4; ++e)
            den[(size_t)s * NN + i0b + w * 16 + q * 4 + e] = accR[e];
    }

    // partial numerator: C layout row r = q*4+e, col = fg*16+cl
    float* nrow = num + (size_t)s * NN * FD;
    #pragma unroll
    for (int e = 0; e < 4; ++e) {
        int r = i0b + w * 16 + q * 4 + e;
        #pragma unroll
        for (int fg = 0; fg < 16; ++fg)
            nrow[(size_t)r * FD + fg * 16 + cl] = acc[fg][e];
    }
}

// ---------------- Kernel 3: combine j-split partials ----------------
__global__ __launch_bounds__(256) void combine_kernel(const float* __restrict__ num,
                                                      const float* __restrict__ den,
                                                      float* __restrict__ out) {
    int idx = blockIdx.x * 256 + threadIdx.x;   // 2M elems; i uniform per block
    int i = idx >> 8;
    float nsum = 0.f, dsum = 0.f;
    #pragma unroll
    for (int s = 0; s < SPLIT; ++s) {
        nsum += num[(size_t)s * NN * FD + idx];
        dsum += den[(size_t)s * NN + i];
    }
    out[idx] = nsum / dsum;
}

extern "C" void kernel_launch(void* const* d_in, const int* in_sizes, int n_in,
                              void* d_out, int out_size, void* d_ws, size_t ws_size,
                              hipStream_t stream) {
    const float* h   = (const float*)d_in[0];
    const int*   adj = (const int*)d_in[1];
    const float* W   = (const float*)d_in[2];
    const float* b   = (const float*)d_in[3];
    const float* a   = (const float*)d_in[4];
    float* out = (float*)d_out;

    char* ws = (char*)d_ws;
    unsigned short* PBu = (unsigned short*)ws;                          // 4 MB packed Wh fragments
    unsigned short* WbT = (unsigned short*)(ws + (4u << 20));           // 128 KB
    float* f1p = (float*)(ws + (4u << 20) + (128u << 10));              // 32 KB
    float* f2p = f1p + NN;                                              // 32 KB
    float* den = f2p + NN;                                              // SPLIT*NN f32 = 256 KB
    float* num = (float*)(ws + (24u << 20));                            // SPLIT*8 MB = 64 MB

    wtrans_kernel<<<256, 256, 0, stream>>>(W, WbT);
    gemm1_kernel<<<256, 256, 0, stream>>>(h, WbT, b, a, PBu, f1p, f2p);
    gat_kernel<<<128 * SPLIT, 256, 0, stream>>>(adj, PBu, f1p, f2p, num, den);
    combine_kernel<<<NN * FD / 256, 256, 0, stream>>>(num, den, out);
}